// Round 4
// baseline (689.776 us; speedup 1.0000x reference)
//
#include <hip/hip_runtime.h>

#define N_NODES 100000
#define N_EDGES 1600000
#define NCLS 40
#define CCAP 24            // per-class slot capacity (Poisson(4) per class; max~17 over 400k bins)
#define SLAB (4 * CCAP)    // 96 ints per node

typedef unsigned short u16;
typedef unsigned int u32;

static inline size_t align256(size_t x) { return (x + 255) & ~(size_t)255; }

__device__ __forceinline__ float bf2f(u16 h) { return __uint_as_float(((u32)h) << 16); }
__device__ __forceinline__ u16 f2bf(float f) {
    u32 u = __float_as_uint(f);
    u += 0x7FFFu + ((u >> 16) & 1u);  // round-to-nearest-even
    return (u16)(u >> 16);
}

// ---------- edge pass: class-spread histograms + src-only scatter; conversion fused ----------
#define EPA_BLOCKS 1563   // ceil(400000/256) edge-quad threads
#define CONV_BLOCKS 6250  // 100000*64/4/256

__global__ void epA_conv(const int* __restrict__ src, const int* __restrict__ dst,
                         int* __restrict__ deg4, int* __restrict__ fill4,
                         int* __restrict__ pairs,
                         const float* __restrict__ x, u16* __restrict__ xb) {
    if (blockIdx.x >= EPA_BLOCKS) {
        // fused fp32->bf16 conversion of x (independent work; hides atomic latency)
        int i = (blockIdx.x - EPA_BLOCKS) * 256 + threadIdx.x;  // 4 floats/thread
        float4 v = *(const float4*)(x + (size_t)i * 4);
        ushort4 o;
        o.x = f2bf(v.x); o.y = f2bf(v.y); o.z = f2bf(v.z); o.w = f2bf(v.w);
        *(ushort4*)(xb + (size_t)i * 4) = o;
        return;
    }
    int t = blockIdx.x * 256 + threadIdx.x;
    int e0 = t * 4;
    if (e0 >= N_EDGES) return;
    int4 s4 = *(const int4*)(src + e0);
    int4 d4 = *(const int4*)(dst + e0);
#pragma unroll
    for (int i = 0; i < 4; ++i) {  // class j == i (e0 % 4 == 0)
        int s = ((const int*)&s4)[i], d = ((const int*)&d4)[i];
        if (s != d) {
            atomicAdd(&deg4[i * N_NODES + s], 1);
            int slot = atomicAdd(&fill4[i * N_NODES + d], 1);
            if (slot < CCAP) pairs[d * SLAB + i * CCAP + slot] = s;
        }
    }
}

// ---------- per-node: dis = 1/sqrt(deg); pack 4 class counts into one u32 ----------
__global__ void node_pass(const int* __restrict__ deg4, const int* __restrict__ fill4,
                          float* __restrict__ dis, u32* __restrict__ cnts) {
    int i = blockIdx.x * blockDim.x + threadIdx.x;
    if (i >= N_NODES) return;
    int dg = deg4[i] + deg4[N_NODES + i] + deg4[2 * N_NODES + i] + deg4[3 * N_NODES + i];
    dis[i] = dg > 0 ? 1.0f / sqrtf((float)dg) : 0.0f;
    u32 pk = 0;
#pragma unroll
    for (int j = 0; j < 4; ++j) {
        int c = fill4[j * N_NODES + i];
        if (c > CCAP) c = CCAP;
        pk |= (u32)c << (8 * j);
    }
    cnts[i] = pk;
}

// ---------- SPMM gather (one wave/node, lane = feature), weights on the fly ----------
// acc = sum_e dis[s_e] * in[s_e, lane];  v = -dis[node] * acc
// outb ? outb = bf16(v)  ;  outf ? outf = 2*v - sub   (Tx2/Th2 form)
__global__ __launch_bounds__(256) void spmm(const u16* __restrict__ in,
                                            const float* __restrict__ dis,
                                            const u32* __restrict__ cnts,
                                            const int* __restrict__ pairs,
                                            const float* __restrict__ sub,
                                            float* __restrict__ outf,
                                            u16* __restrict__ outb) {
    int node = (blockIdx.x * blockDim.x + threadIdx.x) >> 6;
    int lane = threadIdx.x & 63;
    if (node >= N_NODES) return;
    u32 pk = cnts[node];
    float acc = 0.0f;
#pragma unroll
    for (int j = 0; j < 4; ++j) {
        int cj = (pk >> (8 * j)) & 0xFF;
        const int* lst = pairs + node * SLAB + j * CCAP;
        int e = 0;
        for (; e + 4 <= cj; e += 4) {
            int4 s = *(const int4*)(lst + e);           // wave-uniform 16B (broadcast)
            float w0 = dis[s.x], w1 = dis[s.y], w2 = dis[s.z], w3 = dis[s.w];
            float r0 = bf2f(in[((size_t)s.x << 6) | lane]);
            float r1 = bf2f(in[((size_t)s.y << 6) | lane]);
            float r2 = bf2f(in[((size_t)s.z << 6) | lane]);
            float r3 = bf2f(in[((size_t)s.w << 6) | lane]);
            acc = fmaf(w0, r0, acc);
            acc = fmaf(w1, r1, acc);
            acc = fmaf(w2, r2, acc);
            acc = fmaf(w3, r3, acc);
        }
        for (; e < cj; ++e) {  // uniform across wave (lane only picks feature): no divergence
            int s = lst[e];
            acc = fmaf(dis[s], bf2f(in[((size_t)s << 6) | lane]), acc);
        }
    }
    float v = -dis[node] * acc;
    int o = (node << 6) | lane;
    if (outf) outf[o] = 2.0f * v - sub[o];
    if (outb) outb[o] = f2bf(v);
}

// ---------- dense: C[64 x ncols] = [A0|A1|A2] @ W[192 x ncols] ----------
#define AS_STRIDE 100

__device__ __forceinline__ void stage_half(float (*As)[AS_STRIDE], float (*Wl)[64],
                                           const float* __restrict__ A0,
                                           const u16* __restrict__ A1,
                                           const float* __restrict__ A2,
                                           const float* __restrict__ W, int half,
                                           int base, int ncols_w) {
    int tid = threadIdx.x;
    for (int idx = tid; idx < 96 * 64; idx += 256) {
        int k = idx >> 6, j = idx & 63;
        float v = 0.0f;
        if (j < ncols_w) v = W[(half * 96 + k) * ncols_w + j];
        Wl[k][j] = v;
    }
    if (half == 0) {
        for (int idx = tid; idx < 64 * 64; idx += 256) {
            int n = idx >> 6, c = idx & 63;
            int row = base + n;
            if (row >= N_NODES) row = N_NODES - 1;
            As[n][c] = A0[((size_t)row << 6) | c];
        }
        for (int idx = tid; idx < 64 * 32; idx += 256) {
            int n = idx >> 5, c = idx & 31;
            int row = base + n;
            if (row >= N_NODES) row = N_NODES - 1;
            As[n][64 + c] = bf2f(A1[((size_t)row << 6) | c]);
        }
    } else {
        for (int idx = tid; idx < 64 * 32; idx += 256) {
            int n = idx >> 5, c = idx & 31;
            int row = base + n;
            if (row >= N_NODES) row = N_NODES - 1;
            As[n][c] = bf2f(A1[((size_t)row << 6) | (32 + c)]);
        }
        for (int idx = tid; idx < 64 * 64; idx += 256) {
            int n = idx >> 6, c = idx & 63;
            int row = base + n;
            if (row >= N_NODES) row = N_NODES - 1;
            As[n][32 + c] = A2[((size_t)row << 6) | c];
        }
    }
}

__device__ __forceinline__ void mac_half(const float (*As)[AS_STRIDE],
                                         const float (*Wl)[64], int n0, int j0,
                                         float acc[4][4]) {
#pragma unroll 2
    for (int k = 0; k < 96; k += 4) {
        float a[4][4], w[4][4];
#pragma unroll
        for (int i = 0; i < 4; ++i)
            *(float4*)&a[i][0] = *(const float4*)&As[n0 + i][k];
#pragma unroll
        for (int r = 0; r < 4; ++r)
            *(float4*)&w[r][0] = *(const float4*)&Wl[k + r][j0];
#pragma unroll
        for (int r = 0; r < 4; ++r)
#pragma unroll
            for (int i = 0; i < 4; ++i)
#pragma unroll
                for (int jj = 0; jj < 4; ++jj)
                    acc[i][jj] = fmaf(a[i][r], w[r][jj], acc[i][jj]);
    }
}

__global__ __launch_bounds__(256) void dense1(const float* __restrict__ A0,
                                              const u16* __restrict__ A1,
                                              const float* __restrict__ A2,
                                              const float* __restrict__ W,
                                              const float* __restrict__ b,
                                              float* __restrict__ h,
                                              u16* __restrict__ hb) {
    __shared__ __align__(16) float As[64][AS_STRIDE];
    __shared__ __align__(16) float Wl[96][64];
    int base = blockIdx.x * 64;
    int n0 = (threadIdx.x >> 4) * 4, j0 = (threadIdx.x & 15) * 4;

    float acc[4][4];
#pragma unroll
    for (int i = 0; i < 4; ++i)
#pragma unroll
        for (int jj = 0; jj < 4; ++jj) acc[i][jj] = b[j0 + jj];

    stage_half(As, Wl, A0, A1, A2, W, 0, base, 64);
    __syncthreads();
    mac_half(As, Wl, n0, j0, acc);
    __syncthreads();
    stage_half(As, Wl, A0, A1, A2, W, 1, base, 64);
    __syncthreads();
    mac_half(As, Wl, n0, j0, acc);

#pragma unroll
    for (int i = 0; i < 4; ++i) {
        int row = base + n0 + i;
        if (row < N_NODES) {
            float4 v;
            v.x = fmaxf(acc[i][0], 0.0f);
            v.y = fmaxf(acc[i][1], 0.0f);
            v.z = fmaxf(acc[i][2], 0.0f);
            v.w = fmaxf(acc[i][3], 0.0f);
            *(float4*)&h[((size_t)row << 6) | j0] = v;
            ushort4 hv;
            hv.x = f2bf(v.x); hv.y = f2bf(v.y); hv.z = f2bf(v.z); hv.w = f2bf(v.w);
            *(ushort4*)&hb[((size_t)row << 6) | j0] = hv;
        }
    }
}

__global__ __launch_bounds__(256) void dense2(const float* __restrict__ A0,
                                              const u16* __restrict__ A1,
                                              const float* __restrict__ A2,
                                              const float* __restrict__ W,
                                              const float* __restrict__ b,
                                              float* __restrict__ out) {
    __shared__ __align__(16) float As[64][AS_STRIDE];
    __shared__ __align__(16) float Wl[96][64];
    int base = blockIdx.x * 64;
    int n0 = (threadIdx.x >> 4) * 4, j0 = (threadIdx.x & 15) * 4;

    float acc[4][4];
#pragma unroll
    for (int i = 0; i < 4; ++i)
#pragma unroll
        for (int jj = 0; jj < 4; ++jj)
            acc[i][jj] = (j0 + jj < NCLS) ? b[j0 + jj] : -1e30f;

    stage_half(As, Wl, A0, A1, A2, W, 0, base, NCLS);
    __syncthreads();
    mac_half(As, Wl, n0, j0, acc);
    __syncthreads();
    stage_half(As, Wl, A0, A1, A2, W, 1, base, NCLS);
    __syncthreads();
    mac_half(As, Wl, n0, j0, acc);

    __syncthreads();
    float(*Ls)[64] = (float(*)[64]) & As[0][0];
#pragma unroll
    for (int i = 0; i < 4; ++i) *(float4*)&Ls[n0 + i][j0] = *(float4*)&acc[i][0];
    __syncthreads();

    int wv = threadIdx.x >> 6, lane = threadIdx.x & 63;
    for (int r = 0; r < 16; ++r) {
        int n = wv * 16 + r;
        int row = base + n;
        float v = (lane < NCLS) ? Ls[n][lane] : -1e30f;
        float m = v;
        for (int off = 32; off; off >>= 1) m = fmaxf(m, __shfl_xor(m, off));
        float ex = (lane < NCLS) ? expf(v - m) : 0.0f;
        float s = ex;
        for (int off = 32; off; off >>= 1) s += __shfl_xor(s, off);
        if (lane < NCLS && row < N_NODES) out[(size_t)row * NCLS + lane] = ex / s;
    }
}

// ---------------- host ----------------

extern "C" void kernel_launch(void* const* d_in, const int* in_sizes, int n_in,
                              void* d_out, int out_size, void* d_ws, size_t ws_size,
                              hipStream_t stream) {
    const float* x = (const float*)d_in[0];
    const int* edge_index = (const int*)d_in[1];
    const float* W1 = (const float*)d_in[2];
    const float* b1 = (const float*)d_in[3];
    const float* W2 = (const float*)d_in[4];
    const float* b2 = (const float*)d_in[5];
    float* out = (float*)d_out;

    const int* src = edge_index;
    const int* dst = edge_index + N_EDGES;

    char* ws = (char*)d_ws;
    size_t off = 0;
    auto carve = [&](size_t bytes) -> void* {
        void* p = ws + off;
        off = align256(off + bytes);
        return p;
    };
    // zero-every-call region first (class-spread histograms)
    int* deg4 = (int*)carve((size_t)4 * N_NODES * 4);   // 1.6 MB
    int* fill4 = (int*)carve((size_t)4 * N_NODES * 4);  // 1.6 MB
    size_t zero_bytes = off;
    float* dis = (float*)carve((size_t)N_NODES * 4);
    u32* cnts = (u32*)carve((size_t)N_NODES * 4);
    int* pairs = (int*)carve((size_t)N_NODES * SLAB * 4);       // 38.4 MB (src only)
    u16* xb = (u16*)carve((size_t)N_NODES * 64 * 2);            // 12.8 MB; reused as hb
    u16* tx1b = (u16*)carve((size_t)N_NODES * 64 * 2);          // 12.8 MB; reused as th1b
    float* t2 = (float*)carve((size_t)N_NODES * 64 * 4);        // 25.6 MB; reused as th2
    float* h = (float*)carve((size_t)N_NODES * 64 * 4);         // 25.6 MB
    u16* hb = xb;
    u16* th1b = tx1b;
    float* th2 = t2;
    // total ~119 MB (< proven available ~130 MB)

    const int NB = (N_NODES + 255) / 256;      // 391
    const int WV = (N_NODES * 64) / 256;       // 25000
    const int TB = (N_NODES + 63) / 64;        // 1563

    hipMemsetAsync(d_ws, 0, zero_bytes, stream);

    epA_conv<<<EPA_BLOCKS + CONV_BLOCKS, 256, 0, stream>>>(src, dst, deg4, fill4, pairs, x, xb);
    node_pass<<<NB, 256, 0, stream>>>(deg4, fill4, dis, cnts);

    // layer 1
    spmm<<<WV, 256, 0, stream>>>(xb, dis, cnts, pairs, nullptr, nullptr, tx1b);   // Tx1
    spmm<<<WV, 256, 0, stream>>>(tx1b, dis, cnts, pairs, x, t2, nullptr);         // Tx2 = 2*L.Tx1 - x
    dense1<<<TB, 256, 0, stream>>>(x, tx1b, t2, W1, b1, h, hb);

    // layer 2 (buffer reuse: xb->hb, tx1b->th1b, t2->th2)
    spmm<<<WV, 256, 0, stream>>>(hb, dis, cnts, pairs, nullptr, nullptr, th1b);   // Th1
    spmm<<<WV, 256, 0, stream>>>(th1b, dis, cnts, pairs, h, th2, nullptr);        // Th2
    dense2<<<TB, 256, 0, stream>>>(h, th1b, th2, W2, b2, out);
}

// Round 5
// 523.739 us; speedup vs baseline: 1.3170x; 1.3170x over previous
//
#include <hip/hip_runtime.h>

#define N_NODES 100000
#define N_EDGES 1600000
#define NCLS 40
#define SLAB 48            // max in-degree over 100k Poisson(16) nodes ~ 40; P(>=48) ~ 6e-11
#define DUMMY N_NODES      // pad source id; dis[DUMMY] = 0

typedef unsigned short u16;
typedef unsigned int u32;

static inline size_t align256(size_t x) { return (x + 255) & ~(size_t)255; }

__device__ __forceinline__ float bf2f(u16 h) { return __uint_as_float(((u32)h) << 16); }
__device__ __forceinline__ u16 f2bf(float f) {
    u32 u = __float_as_uint(f);
    u += 0x7FFFu + ((u >> 16) & 1u);  // round-to-nearest-even
    return (u16)(u >> 16);
}

// ---------- merged edge pass (histograms + compact src-only scatter) + fused x->bf16 ----------
#define EPA_BLOCKS 1563   // ceil(400000 edge-quad threads / 256)
#define CONV_BLOCKS 6250  // 100000*64/4/256

__global__ __launch_bounds__(256) void epA_conv(const int* __restrict__ src,
                                                const int* __restrict__ dst,
                                                int* __restrict__ deg, int* __restrict__ fill,
                                                int* __restrict__ pairs,
                                                const float* __restrict__ x,
                                                u16* __restrict__ xb) {
    if (blockIdx.x >= EPA_BLOCKS) {
        // independent fp32->bf16 conversion rides along to fill idle issue slots
        int i = (blockIdx.x - EPA_BLOCKS) * 256 + threadIdx.x;  // 4 floats/thread
        float4 v = *(const float4*)(x + (size_t)i * 4);
        ushort4 o;
        o.x = f2bf(v.x); o.y = f2bf(v.y); o.z = f2bf(v.z); o.w = f2bf(v.w);
        *(ushort4*)(xb + (size_t)i * 4) = o;
        return;
    }
    int t = blockIdx.x * 256 + threadIdx.x;
    int e0 = t * 4;
    if (e0 >= N_EDGES) return;
    int4 s4 = *(const int4*)(src + e0);
    int4 d4 = *(const int4*)(dst + e0);
#pragma unroll
    for (int i = 0; i < 4; ++i) {
        int s = ((const int*)&s4)[i], d = ((const int*)&d4)[i];
        if (s != d) {
            atomicAdd(&deg[s], 1);                    // out-degree (src role) -> dis
            int slot = atomicAdd(&fill[d], 1);        // in-list slot (dst role)
            if (slot < SLAB) pairs[d * SLAB + slot] = s;
        }
    }
}

// ---------- per-node: dis = 1/sqrt(deg); pad list to multiple of 8 with DUMMY ----------
__global__ void node_pass(const int* __restrict__ deg, const int* __restrict__ fill,
                          float* __restrict__ dis, int* __restrict__ cnt8,
                          int* __restrict__ pairs) {
    int i = blockIdx.x * blockDim.x + threadIdx.x;
    if (i >= N_NODES) return;
    int dg = deg[i];
    dis[i] = dg > 0 ? 1.0f / sqrtf((float)dg) : 0.0f;
    if (i == 0) dis[DUMMY] = 0.0f;
    int c = min(fill[i], SLAB);
    int c8 = (c + 7) & ~7;
    cnt8[i] = c8;
    for (int e = c; e < c8; ++e) pairs[i * SLAB + e] = DUMMY;
}

// ---------- SPMM gather (one wave/node, lane = feature), weights on the fly ----------
// acc = sum_e dis[s_e] * in[s_e, lane];  v = -dis[node] * acc
// outb -> bf16(v); outf -> 2*v - sub (fp32 Tx2/Th2 form)
__global__ __launch_bounds__(256) void spmm(const u16* __restrict__ in,
                                            const float* __restrict__ dis,
                                            const int* __restrict__ cnt8,
                                            const int* __restrict__ pairs,
                                            const float* __restrict__ sub,
                                            float* __restrict__ outf,
                                            u16* __restrict__ outb) {
    int node = (blockIdx.x * 256 + threadIdx.x) >> 6;
    int lane = threadIdx.x & 63;
    if (node >= N_NODES) return;
    int c8 = cnt8[node];
    const int* lst = pairs + node * SLAB;
    float acc = 0.0f;
    for (int e = 0; e < c8; e += 8) {
        int4 sa = *(const int4*)(lst + e);      // wave-uniform 16B broadcast
        int4 sb = *(const int4*)(lst + e + 4);
        float w0 = dis[sa.x], w1 = dis[sa.y], w2 = dis[sa.z], w3 = dis[sa.w];
        float w4 = dis[sb.x], w5 = dis[sb.y], w6 = dis[sb.z], w7 = dis[sb.w];
        float r0 = bf2f(in[((size_t)sa.x << 6) | lane]);
        float r1 = bf2f(in[((size_t)sa.y << 6) | lane]);
        float r2 = bf2f(in[((size_t)sa.z << 6) | lane]);
        float r3 = bf2f(in[((size_t)sa.w << 6) | lane]);
        float r4 = bf2f(in[((size_t)sb.x << 6) | lane]);
        float r5 = bf2f(in[((size_t)sb.y << 6) | lane]);
        float r6 = bf2f(in[((size_t)sb.z << 6) | lane]);
        float r7 = bf2f(in[((size_t)sb.w << 6) | lane]);
        acc = fmaf(w0, r0, acc);
        acc = fmaf(w1, r1, acc);
        acc = fmaf(w2, r2, acc);
        acc = fmaf(w3, r3, acc);
        acc = fmaf(w4, r4, acc);
        acc = fmaf(w5, r5, acc);
        acc = fmaf(w6, r6, acc);
        acc = fmaf(w7, r7, acc);
    }
    float v = -dis[node] * acc;
    int o = (node << 6) | lane;
    if (outb) outb[o] = f2bf(v);
    if (outf) outf[o] = 2.0f * v - sub[o];
}

// ---------- dense: C[64 x ncols] = [A0|A1|A2] @ W[192 x ncols] (round-3 proven) ----------
#define AS_STRIDE 100

__device__ __forceinline__ void stage_half(float (*As)[AS_STRIDE], float (*Wl)[64],
                                           const float* __restrict__ A0,
                                           const u16* __restrict__ A1,
                                           const float* __restrict__ A2,
                                           const float* __restrict__ W, int half,
                                           int base, int ncols_w) {
    int tid = threadIdx.x;
    for (int idx = tid; idx < 96 * 64; idx += 256) {
        int k = idx >> 6, j = idx & 63;
        float v = 0.0f;
        if (j < ncols_w) v = W[(half * 96 + k) * ncols_w + j];
        Wl[k][j] = v;
    }
    if (half == 0) {
        for (int idx = tid; idx < 64 * 64; idx += 256) {
            int n = idx >> 6, c = idx & 63;
            int row = base + n;
            if (row >= N_NODES) row = N_NODES - 1;
            As[n][c] = A0[((size_t)row << 6) | c];
        }
        for (int idx = tid; idx < 64 * 32; idx += 256) {
            int n = idx >> 5, c = idx & 31;
            int row = base + n;
            if (row >= N_NODES) row = N_NODES - 1;
            As[n][64 + c] = bf2f(A1[((size_t)row << 6) | c]);
        }
    } else {
        for (int idx = tid; idx < 64 * 32; idx += 256) {
            int n = idx >> 5, c = idx & 31;
            int row = base + n;
            if (row >= N_NODES) row = N_NODES - 1;
            As[n][c] = bf2f(A1[((size_t)row << 6) | (32 + c)]);
        }
        for (int idx = tid; idx < 64 * 64; idx += 256) {
            int n = idx >> 6, c = idx & 63;
            int row = base + n;
            if (row >= N_NODES) row = N_NODES - 1;
            As[n][32 + c] = A2[((size_t)row << 6) | c];
        }
    }
}

__device__ __forceinline__ void mac_half(const float (*As)[AS_STRIDE],
                                         const float (*Wl)[64], int n0, int j0,
                                         float acc[4][4]) {
#pragma unroll 2
    for (int k = 0; k < 96; k += 4) {
        float a[4][4], w[4][4];
#pragma unroll
        for (int i = 0; i < 4; ++i)
            *(float4*)&a[i][0] = *(const float4*)&As[n0 + i][k];
#pragma unroll
        for (int r = 0; r < 4; ++r)
            *(float4*)&w[r][0] = *(const float4*)&Wl[k + r][j0];
#pragma unroll
        for (int r = 0; r < 4; ++r)
#pragma unroll
            for (int i = 0; i < 4; ++i)
#pragma unroll
                for (int jj = 0; jj < 4; ++jj)
                    acc[i][jj] = fmaf(a[i][r], w[r][jj], acc[i][jj]);
    }
}

__global__ __launch_bounds__(256) void dense1(const float* __restrict__ A0,
                                              const u16* __restrict__ A1,
                                              const float* __restrict__ A2,
                                              const float* __restrict__ W,
                                              const float* __restrict__ b,
                                              float* __restrict__ h,
                                              u16* __restrict__ hb) {
    __shared__ __align__(16) float As[64][AS_STRIDE];
    __shared__ __align__(16) float Wl[96][64];
    int base = blockIdx.x * 64;
    int n0 = (threadIdx.x >> 4) * 4, j0 = (threadIdx.x & 15) * 4;

    float acc[4][4];
#pragma unroll
    for (int i = 0; i < 4; ++i)
#pragma unroll
        for (int jj = 0; jj < 4; ++jj) acc[i][jj] = b[j0 + jj];

    stage_half(As, Wl, A0, A1, A2, W, 0, base, 64);
    __syncthreads();
    mac_half(As, Wl, n0, j0, acc);
    __syncthreads();
    stage_half(As, Wl, A0, A1, A2, W, 1, base, 64);
    __syncthreads();
    mac_half(As, Wl, n0, j0, acc);

#pragma unroll
    for (int i = 0; i < 4; ++i) {
        int row = base + n0 + i;
        if (row < N_NODES) {
            float4 v;
            v.x = fmaxf(acc[i][0], 0.0f);
            v.y = fmaxf(acc[i][1], 0.0f);
            v.z = fmaxf(acc[i][2], 0.0f);
            v.w = fmaxf(acc[i][3], 0.0f);
            *(float4*)&h[((size_t)row << 6) | j0] = v;
            ushort4 hv;
            hv.x = f2bf(v.x); hv.y = f2bf(v.y); hv.z = f2bf(v.z); hv.w = f2bf(v.w);
            *(ushort4*)&hb[((size_t)row << 6) | j0] = hv;
        }
    }
}

__global__ __launch_bounds__(256) void dense2(const float* __restrict__ A0,
                                              const u16* __restrict__ A1,
                                              const float* __restrict__ A2,
                                              const float* __restrict__ W,
                                              const float* __restrict__ b,
                                              float* __restrict__ out) {
    __shared__ __align__(16) float As[64][AS_STRIDE];
    __shared__ __align__(16) float Wl[96][64];
    int base = blockIdx.x * 64;
    int n0 = (threadIdx.x >> 4) * 4, j0 = (threadIdx.x & 15) * 4;

    float acc[4][4];
#pragma unroll
    for (int i = 0; i < 4; ++i)
#pragma unroll
        for (int jj = 0; jj < 4; ++jj)
            acc[i][jj] = (j0 + jj < NCLS) ? b[j0 + jj] : -1e30f;

    stage_half(As, Wl, A0, A1, A2, W, 0, base, NCLS);
    __syncthreads();
    mac_half(As, Wl, n0, j0, acc);
    __syncthreads();
    stage_half(As, Wl, A0, A1, A2, W, 1, base, NCLS);
    __syncthreads();
    mac_half(As, Wl, n0, j0, acc);

    __syncthreads();
    float(*Ls)[64] = (float(*)[64]) & As[0][0];
#pragma unroll
    for (int i = 0; i < 4; ++i) *(float4*)&Ls[n0 + i][j0] = *(float4*)&acc[i][0];
    __syncthreads();

    int wv = threadIdx.x >> 6, lane = threadIdx.x & 63;
    for (int r = 0; r < 16; ++r) {
        int n = wv * 16 + r;
        int row = base + n;
        float v = (lane < NCLS) ? Ls[n][lane] : -1e30f;
        float m = v;
        for (int off = 32; off; off >>= 1) m = fmaxf(m, __shfl_xor(m, off));
        float ex = (lane < NCLS) ? expf(v - m) : 0.0f;
        float s = ex;
        for (int off = 32; off; off >>= 1) s += __shfl_xor(s, off);
        if (lane < NCLS && row < N_NODES) out[(size_t)row * NCLS + lane] = ex / s;
    }
}

// ---------------- host ----------------

extern "C" void kernel_launch(void* const* d_in, const int* in_sizes, int n_in,
                              void* d_out, int out_size, void* d_ws, size_t ws_size,
                              hipStream_t stream) {
    const float* x = (const float*)d_in[0];
    const int* edge_index = (const int*)d_in[1];
    const float* W1 = (const float*)d_in[2];
    const float* b1 = (const float*)d_in[3];
    const float* W2 = (const float*)d_in[4];
    const float* b2 = (const float*)d_in[5];
    float* out = (float*)d_out;

    const int* src = edge_index;
    const int* dst = edge_index + N_EDGES;

    char* ws = (char*)d_ws;
    size_t off = 0;
    auto carve = [&](size_t bytes) -> void* {
        void* p = ws + off;
        off = align256(off + bytes);
        return p;
    };
    // zero-every-call region first
    int* deg = (int*)carve((size_t)N_NODES * 4);     // 400 KB
    int* fill = (int*)carve((size_t)N_NODES * 4);    // 400 KB
    size_t zero_bytes = off;
    float* dis = (float*)carve((size_t)(N_NODES + 1) * 4);
    int* cnt8 = (int*)carve((size_t)N_NODES * 4);
    int* pairs = (int*)carve((size_t)N_NODES * SLAB * 4);          // 19.2 MB (src only)
    u16* xb = (u16*)carve((size_t)(N_NODES + 1) * 64 * 2);         // 12.8 MB
    u16* tx1b = (u16*)carve((size_t)(N_NODES + 1) * 64 * 2);       // 12.8 MB; reused as th1b
    u16* hb = (u16*)carve((size_t)(N_NODES + 1) * 64 * 2);         // 12.8 MB
    float* t2 = (float*)carve((size_t)N_NODES * 64 * 4);           // 25.6 MB; reused as th2
    float* h = (float*)carve((size_t)N_NODES * 64 * 4);            // 25.6 MB
    u16* th1b = tx1b;  // tx1b last read in dense1, before spmm3 writes th1b
    float* th2 = t2;   // t2  last read in dense1, before spmm4 writes th2
    // total ~111 MB

    const int NB = (N_NODES + 255) / 256;   // 391
    const int WV = (N_NODES * 64) / 256;    // 25000 (one wave per node)
    const int TB = (N_NODES + 63) / 64;     // 1563

    hipMemsetAsync(d_ws, 0, zero_bytes, stream);

    epA_conv<<<EPA_BLOCKS + CONV_BLOCKS, 256, 0, stream>>>(src, dst, deg, fill, pairs, x, xb);
    node_pass<<<NB, 256, 0, stream>>>(deg, fill, dis, cnt8, pairs);

    // layer 1
    spmm<<<WV, 256, 0, stream>>>(xb, dis, cnt8, pairs, nullptr, nullptr, tx1b);   // Tx1
    spmm<<<WV, 256, 0, stream>>>(tx1b, dis, cnt8, pairs, x, t2, nullptr);         // Tx2 = 2*L.Tx1 - x
    dense1<<<TB, 256, 0, stream>>>(x, tx1b, t2, W1, b1, h, hb);

    // layer 2
    spmm<<<WV, 256, 0, stream>>>(hb, dis, cnt8, pairs, nullptr, nullptr, th1b);   // Th1
    spmm<<<WV, 256, 0, stream>>>(th1b, dis, cnt8, pairs, h, th2, nullptr);        // Th2
    dense2<<<TB, 256, 0, stream>>>(h, th1b, th2, W2, b2, out);
}

// Round 6
// 478.426 us; speedup vs baseline: 1.4418x; 1.0947x over previous
//
#include <hip/hip_runtime.h>

#define N_NODES 100000
#define N_EDGES 1600000
#define NCLS 40
#define NBUCK 196          // ceil(100000/512) buckets of 512 nodes; bucket = id >> 9
#define CAPE 8960          // per-bucket edge capacity (Binomial mu=8192, sigma~90; mu+8.5s)
#define CAPC 10752         // per-bucket CSR capacity incl. x8 padding (mu~9984, +7.4s)

typedef unsigned short u16;
typedef unsigned int u32;

static inline size_t align256(size_t x) { return (x + 255) & ~(size_t)255; }

__device__ __forceinline__ float bf2f(u16 h) { return __uint_as_float(((u32)h) << 16); }
__device__ __forceinline__ u16 f2bf(float f) {
    u32 u = __float_as_uint(f);
    u += 0x7FFFu + ((u >> 16) & 1u);  // round-to-nearest-even
    return (u16)(u >> 16);
}

// ---------- pass 1: LDS-histogram partition by bucket + fused x->bf16 ----------
// Only ~153k global atomics (one per block x touched bucket) instead of 3.2M.
#define PS_BLOCKS 391     // 391 * 4096 edges
#define CONV_BLOCKS 6250  // 100000*64/4/256

__global__ __launch_bounds__(256) void pscatter_conv(const int* __restrict__ src,
                                                     const int* __restrict__ dst,
                                                     int* __restrict__ gFillD,
                                                     int* __restrict__ gFillS,
                                                     int2* __restrict__ partD,
                                                     int* __restrict__ partS,
                                                     const float* __restrict__ x,
                                                     u16* __restrict__ xb) {
    if (blockIdx.x >= PS_BLOCKS) {
        int i = (blockIdx.x - PS_BLOCKS) * 256 + threadIdx.x;  // 4 floats/thread
        float4 v = *(const float4*)(x + (size_t)i * 4);
        ushort4 o;
        o.x = f2bf(v.x); o.y = f2bf(v.y); o.z = f2bf(v.z); o.w = f2bf(v.w);
        *(ushort4*)(xb + (size_t)i * 4) = o;
        return;
    }
    __shared__ int histD[NBUCK], histS[NBUCK], chunkD[NBUCK], chunkS[NBUCK];
    int tid = threadIdx.x;
    int base = blockIdx.x * 4096;

    int4 sv[4], dv[4];
#pragma unroll
    for (int j = 0; j < 4; ++j) {
        int idx = base + j * 1024 + tid * 4;
        if (idx < N_EDGES) {
            sv[j] = *(const int4*)(src + idx);
            dv[j] = *(const int4*)(dst + idx);
        } else {
            sv[j] = make_int4(0, 0, 0, 0);  // s==d -> treated as self-loop, dropped
            dv[j] = make_int4(0, 0, 0, 0);
        }
    }

    for (int i = tid; i < NBUCK; i += 256) { histD[i] = 0; histS[i] = 0; }
    __syncthreads();
#pragma unroll
    for (int j = 0; j < 4; ++j)
#pragma unroll
        for (int k = 0; k < 4; ++k) {
            int s = ((const int*)&sv[j])[k], d = ((const int*)&dv[j])[k];
            if (s != d) {
                atomicAdd(&histD[d >> 9], 1);
                atomicAdd(&histS[s >> 9], 1);
            }
        }
    __syncthreads();
    // allocate contiguous chunks per bucket (the only global atomics)
    for (int B = tid; B < NBUCK; B += 256) {
        int cD = histD[B];
        chunkD[B] = cD ? atomicAdd(&gFillD[B], cD) : 0;
        int cS = histS[B];
        chunkS[B] = cS ? atomicAdd(&gFillS[B], cS) : 0;
    }
    __syncthreads();
    for (int i = tid; i < NBUCK; i += 256) { histD[i] = 0; histS[i] = 0; }  // reuse as rank
    __syncthreads();
#pragma unroll
    for (int j = 0; j < 4; ++j)
#pragma unroll
        for (int k = 0; k < 4; ++k) {
            int s = ((const int*)&sv[j])[k], d = ((const int*)&dv[j])[k];
            if (s != d) {
                int bD = d >> 9;
                int r = atomicAdd(&histD[bD], 1);
                int o = chunkD[bD] + r;
                if (o < CAPE) partD[bD * CAPE + o] = make_int2(d, s);
                int bS = s >> 9;
                int r2 = atomicAdd(&histS[bS], 1);
                int o2 = chunkS[bS] + r2;
                if (o2 < CAPE) partS[bS * CAPE + o2] = s;
            }
        }
}

// ---------- pass 2: per-bucket build. Blocks [0,196): CSR+meta; [196,392): deg->dis ----------
__global__ __launch_bounds__(256) void build(const int2* __restrict__ partD,
                                             const int* __restrict__ partS,
                                             const int* __restrict__ gFillD,
                                             const int* __restrict__ gFillS,
                                             int* __restrict__ csr,
                                             int2* __restrict__ meta,
                                             float* __restrict__ dis) {
    __shared__ int cnt[512], loc[512], rnk[512];
    int tid = threadIdx.x;

    if (blockIdx.x >= NBUCK) {
        // src-side: out-degree histogram -> dis
        int B = blockIdx.x - NBUCK;
        for (int i = tid; i < 512; i += 256) cnt[i] = 0;
        __syncthreads();
        int nS = min(gFillS[B], CAPE);
        for (int i = tid; i < nS; i += 256) atomicAdd(&cnt[partS[B * CAPE + i] & 511], 1);
        __syncthreads();
        for (int n = tid; n < 512; n += 256) {
            int node = B * 512 + n;
            if (node < N_NODES) {
                int dg = cnt[n];
                dis[node] = dg > 0 ? 1.0f / sqrtf((float)dg) : 0.0f;
            }
        }
        return;
    }

    int B = blockIdx.x;
    for (int i = tid; i < 512; i += 256) { cnt[i] = 0; rnk[i] = 0; }
    __syncthreads();
    int nD = min(gFillD[B], CAPE);
    for (int i = tid; i < nD; i += 256) atomicAdd(&cnt[partD[B * CAPE + i].x & 511], 1);
    __syncthreads();
    // exclusive scan of x8-padded counts (wave 0 only; 8 bins/lane + shfl scan)
    if (tid < 64) {
        int bb = tid * 8, c8[8], mysum = 0;
#pragma unroll
        for (int j = 0; j < 8; ++j) { c8[j] = (cnt[bb + j] + 7) & ~7; mysum += c8[j]; }
        int incl = mysum;
#pragma unroll
        for (int off = 1; off < 64; off <<= 1) {
            int v = __shfl_up(incl, off);
            if (tid >= off) incl += v;
        }
        int run = incl - mysum;
#pragma unroll
        for (int j = 0; j < 8; ++j) { loc[bb + j] = run; run += c8[j]; }
    }
    __syncthreads();
    for (int n = tid; n < 512; n += 256) {
        int node = B * 512 + n;
        if (node < N_NODES) meta[node] = make_int2(B * CAPC + loc[n], cnt[n]);
    }
    for (int i = tid; i < nD; i += 256) {
        int2 p = partD[B * CAPE + i];
        int ln = p.x & 511;
        int r = atomicAdd(&rnk[ln], 1);
        int pos = loc[ln] + r;
        if (pos < CAPC) csr[B * CAPC + pos] = p.y;
    }
}

// ---------- SPMM gather (one wave/node, lane = feature), weights on the fly ----------
// acc = sum_e dis[s_e] * in[s_e, lane];  v = -dis[node] * acc
// outb -> bf16(v); outf -> 2*v - sub (fp32 Tx2/Th2 form)
__global__ __launch_bounds__(256) void spmm(const u16* __restrict__ in,
                                            const float* __restrict__ dis,
                                            const int2* __restrict__ meta,
                                            const int* __restrict__ csr,
                                            const float* __restrict__ sub,
                                            float* __restrict__ outf,
                                            u16* __restrict__ outb) {
    int node = (blockIdx.x * 256 + threadIdx.x) >> 6;
    int lane = threadIdx.x & 63;
    if (node >= N_NODES) return;
    int2 mt = meta[node];
    int c = mt.y;
    const int* lst = csr + mt.x;  // start is x8-aligned -> 32B-aligned int4 loads
    float acc = 0.0f;
    int e = 0;
    for (; e + 8 <= c; e += 8) {
        int4 sa = *(const int4*)(lst + e);      // wave-uniform 16B broadcast
        int4 sb = *(const int4*)(lst + e + 4);
        float w0 = dis[sa.x], w1 = dis[sa.y], w2 = dis[sa.z], w3 = dis[sa.w];
        float w4 = dis[sb.x], w5 = dis[sb.y], w6 = dis[sb.z], w7 = dis[sb.w];
        float r0 = bf2f(in[((size_t)sa.x << 6) | lane]);
        float r1 = bf2f(in[((size_t)sa.y << 6) | lane]);
        float r2 = bf2f(in[((size_t)sa.z << 6) | lane]);
        float r3 = bf2f(in[((size_t)sa.w << 6) | lane]);
        float r4 = bf2f(in[((size_t)sb.x << 6) | lane]);
        float r5 = bf2f(in[((size_t)sb.y << 6) | lane]);
        float r6 = bf2f(in[((size_t)sb.z << 6) | lane]);
        float r7 = bf2f(in[((size_t)sb.w << 6) | lane]);
        acc = fmaf(w0, r0, acc);
        acc = fmaf(w1, r1, acc);
        acc = fmaf(w2, r2, acc);
        acc = fmaf(w3, r3, acc);
        acc = fmaf(w4, r4, acc);
        acc = fmaf(w5, r5, acc);
        acc = fmaf(w6, r6, acc);
        acc = fmaf(w7, r7, acc);
    }
    for (; e < c; ++e) {
        int s = lst[e];
        acc = fmaf(dis[s], bf2f(in[((size_t)s << 6) | lane]), acc);
    }
    float v = -dis[node] * acc;
    int o = (node << 6) | lane;
    if (outb) outb[o] = f2bf(v);
    if (outf) outf[o] = 2.0f * v - sub[o];
}

// ---------- dense: C[64 x ncols] = [A0|A1|A2] @ W[192 x ncols] (proven) ----------
#define AS_STRIDE 100

__device__ __forceinline__ void stage_half(float (*As)[AS_STRIDE], float (*Wl)[64],
                                           const float* __restrict__ A0,
                                           const u16* __restrict__ A1,
                                           const float* __restrict__ A2,
                                           const float* __restrict__ W, int half,
                                           int base, int ncols_w) {
    int tid = threadIdx.x;
    for (int idx = tid; idx < 96 * 64; idx += 256) {
        int k = idx >> 6, j = idx & 63;
        float v = 0.0f;
        if (j < ncols_w) v = W[(half * 96 + k) * ncols_w + j];
        Wl[k][j] = v;
    }
    if (half == 0) {
        for (int idx = tid; idx < 64 * 64; idx += 256) {
            int n = idx >> 6, c = idx & 63;
            int row = base + n;
            if (row >= N_NODES) row = N_NODES - 1;
            As[n][c] = A0[((size_t)row << 6) | c];
        }
        for (int idx = tid; idx < 64 * 32; idx += 256) {
            int n = idx >> 5, c = idx & 31;
            int row = base + n;
            if (row >= N_NODES) row = N_NODES - 1;
            As[n][64 + c] = bf2f(A1[((size_t)row << 6) | c]);
        }
    } else {
        for (int idx = tid; idx < 64 * 32; idx += 256) {
            int n = idx >> 5, c = idx & 31;
            int row = base + n;
            if (row >= N_NODES) row = N_NODES - 1;
            As[n][c] = bf2f(A1[((size_t)row << 6) | (32 + c)]);
        }
        for (int idx = tid; idx < 64 * 64; idx += 256) {
            int n = idx >> 6, c = idx & 63;
            int row = base + n;
            if (row >= N_NODES) row = N_NODES - 1;
            As[n][32 + c] = A2[((size_t)row << 6) | c];
        }
    }
}

__device__ __forceinline__ void mac_half(const float (*As)[AS_STRIDE],
                                         const float (*Wl)[64], int n0, int j0,
                                         float acc[4][4]) {
#pragma unroll 2
    for (int k = 0; k < 96; k += 4) {
        float a[4][4], w[4][4];
#pragma unroll
        for (int i = 0; i < 4; ++i)
            *(float4*)&a[i][0] = *(const float4*)&As[n0 + i][k];
#pragma unroll
        for (int r = 0; r < 4; ++r)
            *(float4*)&w[r][0] = *(const float4*)&Wl[k + r][j0];
#pragma unroll
        for (int r = 0; r < 4; ++r)
#pragma unroll
            for (int i = 0; i < 4; ++i)
#pragma unroll
                for (int jj = 0; jj < 4; ++jj)
                    acc[i][jj] = fmaf(a[i][r], w[r][jj], acc[i][jj]);
    }
}

__global__ __launch_bounds__(256) void dense1(const float* __restrict__ A0,
                                              const u16* __restrict__ A1,
                                              const float* __restrict__ A2,
                                              const float* __restrict__ W,
                                              const float* __restrict__ b,
                                              float* __restrict__ h,
                                              u16* __restrict__ hb) {
    __shared__ __align__(16) float As[64][AS_STRIDE];
    __shared__ __align__(16) float Wl[96][64];
    int base = blockIdx.x * 64;
    int n0 = (threadIdx.x >> 4) * 4, j0 = (threadIdx.x & 15) * 4;

    float acc[4][4];
#pragma unroll
    for (int i = 0; i < 4; ++i)
#pragma unroll
        for (int jj = 0; jj < 4; ++jj) acc[i][jj] = b[j0 + jj];

    stage_half(As, Wl, A0, A1, A2, W, 0, base, 64);
    __syncthreads();
    mac_half(As, Wl, n0, j0, acc);
    __syncthreads();
    stage_half(As, Wl, A0, A1, A2, W, 1, base, 64);
    __syncthreads();
    mac_half(As, Wl, n0, j0, acc);

#pragma unroll
    for (int i = 0; i < 4; ++i) {
        int row = base + n0 + i;
        if (row < N_NODES) {
            float4 v;
            v.x = fmaxf(acc[i][0], 0.0f);
            v.y = fmaxf(acc[i][1], 0.0f);
            v.z = fmaxf(acc[i][2], 0.0f);
            v.w = fmaxf(acc[i][3], 0.0f);
            *(float4*)&h[((size_t)row << 6) | j0] = v;
            ushort4 hv;
            hv.x = f2bf(v.x); hv.y = f2bf(v.y); hv.z = f2bf(v.z); hv.w = f2bf(v.w);
            *(ushort4*)&hb[((size_t)row << 6) | j0] = hv;
        }
    }
}

__global__ __launch_bounds__(256) void dense2(const float* __restrict__ A0,
                                              const u16* __restrict__ A1,
                                              const float* __restrict__ A2,
                                              const float* __restrict__ W,
                                              const float* __restrict__ b,
                                              float* __restrict__ out) {
    __shared__ __align__(16) float As[64][AS_STRIDE];
    __shared__ __align__(16) float Wl[96][64];
    int base = blockIdx.x * 64;
    int n0 = (threadIdx.x >> 4) * 4, j0 = (threadIdx.x & 15) * 4;

    float acc[4][4];
#pragma unroll
    for (int i = 0; i < 4; ++i)
#pragma unroll
        for (int jj = 0; jj < 4; ++jj)
            acc[i][jj] = (j0 + jj < NCLS) ? b[j0 + jj] : -1e30f;

    stage_half(As, Wl, A0, A1, A2, W, 0, base, NCLS);
    __syncthreads();
    mac_half(As, Wl, n0, j0, acc);
    __syncthreads();
    stage_half(As, Wl, A0, A1, A2, W, 1, base, NCLS);
    __syncthreads();
    mac_half(As, Wl, n0, j0, acc);

    __syncthreads();
    float(*Ls)[64] = (float(*)[64]) & As[0][0];
#pragma unroll
    for (int i = 0; i < 4; ++i) *(float4*)&Ls[n0 + i][j0] = *(float4*)&acc[i][0];
    __syncthreads();

    int wv = threadIdx.x >> 6, lane = threadIdx.x & 63;
    for (int r = 0; r < 16; ++r) {
        int n = wv * 16 + r;
        int row = base + n;
        float v = (lane < NCLS) ? Ls[n][lane] : -1e30f;
        float m = v;
        for (int off = 32; off; off >>= 1) m = fmaxf(m, __shfl_xor(m, off));
        float ex = (lane < NCLS) ? expf(v - m) : 0.0f;
        float s = ex;
        for (int off = 32; off; off >>= 1) s += __shfl_xor(s, off);
        if (lane < NCLS && row < N_NODES) out[(size_t)row * NCLS + lane] = ex / s;
    }
}

// ---------------- host ----------------

extern "C" void kernel_launch(void* const* d_in, const int* in_sizes, int n_in,
                              void* d_out, int out_size, void* d_ws, size_t ws_size,
                              hipStream_t stream) {
    const float* x = (const float*)d_in[0];
    const int* edge_index = (const int*)d_in[1];
    const float* W1 = (const float*)d_in[2];
    const float* b1 = (const float*)d_in[3];
    const float* W2 = (const float*)d_in[4];
    const float* b2 = (const float*)d_in[5];
    float* out = (float*)d_out;

    const int* src = edge_index;
    const int* dst = edge_index + N_EDGES;

    char* ws = (char*)d_ws;
    size_t off = 0;
    auto carve = [&](size_t bytes) -> void* {
        void* p = ws + off;
        off = align256(off + bytes);
        return p;
    };
    // zero-every-call region first (bucket fill counters only - 1.6 KB)
    int* gFillD = (int*)carve((size_t)NBUCK * 4);
    int* gFillS = (int*)carve((size_t)NBUCK * 4);
    size_t zero_bytes = off;
    int2* partD = (int2*)carve((size_t)NBUCK * CAPE * 8);   // 14.0 MB
    int* partS = (int*)carve((size_t)NBUCK * CAPE * 4);     // 7.0 MB
    int* csr = (int*)carve((size_t)NBUCK * CAPC * 4);       // 8.4 MB
    int2* meta = (int2*)carve((size_t)N_NODES * 8);         // 0.8 MB
    float* dis = (float*)carve((size_t)N_NODES * 4);        // 0.4 MB
    u16* xb = (u16*)carve((size_t)N_NODES * 64 * 2);        // 12.8 MB
    u16* tx1b = (u16*)carve((size_t)N_NODES * 64 * 2);      // 12.8 MB; reused as th1b
    u16* hb = (u16*)carve((size_t)N_NODES * 64 * 2);        // 12.8 MB
    float* t2 = (float*)carve((size_t)N_NODES * 64 * 4);    // 25.6 MB; reused as th2
    float* h = (float*)carve((size_t)N_NODES * 64 * 4);     // 25.6 MB
    u16* th1b = tx1b;
    float* th2 = t2;
    // total ~120 MB (round-2 pathA proved >= ~129 MB available)

    const int WV = (N_NODES * 64) / 256;    // 25000 (one wave per node)
    const int TB = (N_NODES + 63) / 64;     // 1563

    hipMemsetAsync(d_ws, 0, zero_bytes, stream);

    pscatter_conv<<<PS_BLOCKS + CONV_BLOCKS, 256, 0, stream>>>(src, dst, gFillD, gFillS,
                                                               partD, partS, x, xb);
    build<<<2 * NBUCK, 256, 0, stream>>>(partD, partS, gFillD, gFillS, csr, meta, dis);

    // layer 1
    spmm<<<WV, 256, 0, stream>>>(xb, dis, meta, csr, nullptr, nullptr, tx1b);   // Tx1
    spmm<<<WV, 256, 0, stream>>>(tx1b, dis, meta, csr, x, t2, nullptr);         // Tx2 = 2*L.Tx1 - x
    dense1<<<TB, 256, 0, stream>>>(x, tx1b, t2, W1, b1, h, hb);

    // layer 2
    spmm<<<WV, 256, 0, stream>>>(hb, dis, meta, csr, nullptr, nullptr, th1b);   // Th1
    spmm<<<WV, 256, 0, stream>>>(th1b, dis, meta, csr, h, th2, nullptr);        // Th2
    dense2<<<TB, 256, 0, stream>>>(h, th1b, th2, W2, b2, out);
}

// Round 7
// 381.111 us; speedup vs baseline: 1.8099x; 1.2553x over previous
//
#include <hip/hip_runtime.h>

#define N_NODES 100000
#define N_EDGES 1600000
#define NCLS 40
#define NBUCK 196          // buckets of 512 nodes; bucket = id >> 9
#define CAPE 8960          // per-bucket edge capacity
#define CAPC 10752         // per-bucket CSR capacity incl. x8 padding

typedef unsigned short u16;
typedef unsigned int u32;
typedef short bf16x8 __attribute__((ext_vector_type(8)));
typedef float f32x4 __attribute__((ext_vector_type(4)));

static inline size_t align256(size_t x) { return (x + 255) & ~(size_t)255; }

__device__ __forceinline__ float bf2f(u16 h) { return __uint_as_float(((u32)h) << 16); }
__device__ __forceinline__ u16 f2bf(float f) {
    u32 u = __float_as_uint(f);
    u += 0x7FFFu + ((u >> 16) & 1u);  // round-to-nearest-even
    return (u16)(u >> 16);
}

// ---------- pass 1: LDS-histogram partition by bucket + fused x->bf16 ----------
#define PS_BLOCKS 391
#define CONV_BLOCKS 6250

__global__ __launch_bounds__(256) void pscatter_conv(const int* __restrict__ src,
                                                     const int* __restrict__ dst,
                                                     int* __restrict__ gFillD,
                                                     int* __restrict__ gFillS,
                                                     int2* __restrict__ partD,
                                                     int* __restrict__ partS,
                                                     const float* __restrict__ x,
                                                     u16* __restrict__ xb) {
    if (blockIdx.x >= PS_BLOCKS) {
        int i = (blockIdx.x - PS_BLOCKS) * 256 + threadIdx.x;  // 4 floats/thread
        float4 v = *(const float4*)(x + (size_t)i * 4);
        ushort4 o;
        o.x = f2bf(v.x); o.y = f2bf(v.y); o.z = f2bf(v.z); o.w = f2bf(v.w);
        *(ushort4*)(xb + (size_t)i * 4) = o;
        return;
    }
    __shared__ int histD[NBUCK], histS[NBUCK], chunkD[NBUCK], chunkS[NBUCK];
    int tid = threadIdx.x;
    int base = blockIdx.x * 4096;

    int4 sv[4], dv[4];
#pragma unroll
    for (int j = 0; j < 4; ++j) {
        int idx = base + j * 1024 + tid * 4;
        if (idx < N_EDGES) {
            sv[j] = *(const int4*)(src + idx);
            dv[j] = *(const int4*)(dst + idx);
        } else {
            sv[j] = make_int4(0, 0, 0, 0);
            dv[j] = make_int4(0, 0, 0, 0);
        }
    }

    for (int i = tid; i < NBUCK; i += 256) { histD[i] = 0; histS[i] = 0; }
    __syncthreads();
#pragma unroll
    for (int j = 0; j < 4; ++j)
#pragma unroll
        for (int k = 0; k < 4; ++k) {
            int s = ((const int*)&sv[j])[k], d = ((const int*)&dv[j])[k];
            if (s != d) {
                atomicAdd(&histD[d >> 9], 1);
                atomicAdd(&histS[s >> 9], 1);
            }
        }
    __syncthreads();
    for (int B = tid; B < NBUCK; B += 256) {
        int cD = histD[B];
        chunkD[B] = cD ? atomicAdd(&gFillD[B], cD) : 0;
        int cS = histS[B];
        chunkS[B] = cS ? atomicAdd(&gFillS[B], cS) : 0;
    }
    __syncthreads();
    for (int i = tid; i < NBUCK; i += 256) { histD[i] = 0; histS[i] = 0; }
    __syncthreads();
#pragma unroll
    for (int j = 0; j < 4; ++j)
#pragma unroll
        for (int k = 0; k < 4; ++k) {
            int s = ((const int*)&sv[j])[k], d = ((const int*)&dv[j])[k];
            if (s != d) {
                int bD = d >> 9;
                int r = atomicAdd(&histD[bD], 1);
                int o = chunkD[bD] + r;
                if (o < CAPE) partD[bD * CAPE + o] = make_int2(d, s);
                int bS = s >> 9;
                int r2 = atomicAdd(&histS[bS], 1);
                int o2 = chunkS[bS] + r2;
                if (o2 < CAPE) partS[bS * CAPE + o2] = s;
            }
        }
}

// ---------- pass 2: per-bucket CSR build (blocks [0,196)) / deg->dis (blocks [196,392)) ----------
__global__ __launch_bounds__(256) void build(const int2* __restrict__ partD,
                                             const int* __restrict__ partS,
                                             const int* __restrict__ gFillD,
                                             const int* __restrict__ gFillS,
                                             int* __restrict__ csr,
                                             int2* __restrict__ meta,
                                             float* __restrict__ dis) {
    __shared__ int cnt[512], loc[512], rnk[512];
    int tid = threadIdx.x;

    if (blockIdx.x >= NBUCK) {
        int B = blockIdx.x - NBUCK;
        for (int i = tid; i < 512; i += 256) cnt[i] = 0;
        __syncthreads();
        int nS = min(gFillS[B], CAPE);
        for (int i = tid; i < nS; i += 256) atomicAdd(&cnt[partS[B * CAPE + i] & 511], 1);
        __syncthreads();
        for (int n = tid; n < 512; n += 256) {
            int node = B * 512 + n;
            if (node < N_NODES) {
                int dg = cnt[n];
                dis[node] = dg > 0 ? 1.0f / sqrtf((float)dg) : 0.0f;
            }
        }
        return;
    }

    int B = blockIdx.x;
    for (int i = tid; i < 512; i += 256) { cnt[i] = 0; rnk[i] = 0; }
    __syncthreads();
    int nD = min(gFillD[B], CAPE);
    for (int i = tid; i < nD; i += 256) atomicAdd(&cnt[partD[B * CAPE + i].x & 511], 1);
    __syncthreads();
    if (tid < 64) {
        int bb = tid * 8, c8[8], mysum = 0;
#pragma unroll
        for (int j = 0; j < 8; ++j) { c8[j] = (cnt[bb + j] + 7) & ~7; mysum += c8[j]; }
        int incl = mysum;
#pragma unroll
        for (int off = 1; off < 64; off <<= 1) {
            int v = __shfl_up(incl, off);
            if (tid >= off) incl += v;
        }
        int run = incl - mysum;
#pragma unroll
        for (int j = 0; j < 8; ++j) { loc[bb + j] = run; run += c8[j]; }
    }
    __syncthreads();
    for (int n = tid; n < 512; n += 256) {
        int node = B * 512 + n;
        if (node < N_NODES) meta[node] = make_int2(B * CAPC + loc[n], cnt[n]);
    }
    for (int i = tid; i < nD; i += 256) {
        int2 p = partD[B * CAPE + i];
        int ln = p.x & 511;
        int r = atomicAdd(&rnk[ln], 1);
        int pos = loc[ln] + r;
        if (pos < CAPC) csr[B * CAPC + pos] = p.y;
    }
}

// ---------- SPMM gather (one wave/node, lane = feature), split hi/lo bf16 output ----------
// acc = sum_e dis[s_e]*in[s_e,lane];  v = -dis[node]*acc
// subf:   v = 2v - subf[o]          (fp32 subtract)
// subh/l: v = 2v - (hi+lo)          (split subtract)
// output: outhi = bf16(v), outlo = bf16(v - outhi)
__global__ __launch_bounds__(256) void spmm(const u16* __restrict__ in,
                                            const float* __restrict__ dis,
                                            const int2* __restrict__ meta,
                                            const int* __restrict__ csr,
                                            const float* __restrict__ subf,
                                            const u16* __restrict__ subh,
                                            const u16* __restrict__ subl,
                                            u16* __restrict__ outhi,
                                            u16* __restrict__ outlo) {
    int node = (blockIdx.x * 256 + threadIdx.x) >> 6;
    int lane = threadIdx.x & 63;
    if (node >= N_NODES) return;
    int2 mt = meta[node];
    int c = mt.y;
    const int* lst = csr + mt.x;
    float acc = 0.0f;
    int e = 0;
    for (; e + 8 <= c; e += 8) {
        int4 sa = *(const int4*)(lst + e);
        int4 sb = *(const int4*)(lst + e + 4);
        float w0 = dis[sa.x], w1 = dis[sa.y], w2 = dis[sa.z], w3 = dis[sa.w];
        float w4 = dis[sb.x], w5 = dis[sb.y], w6 = dis[sb.z], w7 = dis[sb.w];
        float r0 = bf2f(in[((size_t)sa.x << 6) | lane]);
        float r1 = bf2f(in[((size_t)sa.y << 6) | lane]);
        float r2 = bf2f(in[((size_t)sa.z << 6) | lane]);
        float r3 = bf2f(in[((size_t)sa.w << 6) | lane]);
        float r4 = bf2f(in[((size_t)sb.x << 6) | lane]);
        float r5 = bf2f(in[((size_t)sb.y << 6) | lane]);
        float r6 = bf2f(in[((size_t)sb.z << 6) | lane]);
        float r7 = bf2f(in[((size_t)sb.w << 6) | lane]);
        acc = fmaf(w0, r0, acc);
        acc = fmaf(w1, r1, acc);
        acc = fmaf(w2, r2, acc);
        acc = fmaf(w3, r3, acc);
        acc = fmaf(w4, r4, acc);
        acc = fmaf(w5, r5, acc);
        acc = fmaf(w6, r6, acc);
        acc = fmaf(w7, r7, acc);
    }
    for (; e < c; ++e) {
        int s = lst[e];
        acc = fmaf(dis[s], bf2f(in[((size_t)s << 6) | lane]), acc);
    }
    float v = -dis[node] * acc;
    int o = (node << 6) | lane;
    if (subf) v = 2.0f * v - subf[o];
    else if (subh) v = 2.0f * v - (bf2f(subh[o]) + bf2f(subl[o]));
    u16 hh = f2bf(v);
    outhi[o] = hh;
    outlo[o] = f2bf(v - bf2f(hh));
}

// ---------- dense via MFMA with split-bf16 (fp32-equivalent accuracy) ----------
// C[16 x 16] per wave; block = 4 waves = 4 col-groups; A tile 16x192 staged in LDS
// as hi/lo bf16 planes; W kept split in registers; 3 MFMAs per K-chunk (hh, lh, hl).
#define DGRID 1250
#define DNT 5              // 1250 * 5 * 16 = 100000 rows exactly
#define LSTR 200           // u16 per LDS row (192 data + 8 pad -> 400B, bank-balanced)

__global__ __launch_bounds__(256) void dense1_mf(const float* __restrict__ x,
                                                 const u16* __restrict__ a1h,
                                                 const u16* __restrict__ a1l,
                                                 const u16* __restrict__ a2h,
                                                 const u16* __restrict__ a2l,
                                                 const float* __restrict__ W,
                                                 const float* __restrict__ bias,
                                                 u16* __restrict__ ohi,
                                                 u16* __restrict__ olo) {
    __shared__ u16 Ah[16 * LSTR], Al[16 * LSTR];
    const int tid = threadIdx.x, wid = tid >> 6, lane = tid & 63;
    const int lrow = lane & 15, lk8 = (lane >> 4) * 8;
    const int col = wid * 16 + lrow;

    bf16x8 wh[6], wl[6];
#pragma unroll
    for (int c = 0; c < 6; ++c) {
        bf16x8 h, l;
#pragma unroll
        for (int i = 0; i < 8; ++i) {
            float wv = W[(c * 32 + lk8 + i) * 64 + col];
            u16 hb_ = f2bf(wv);
            h[i] = (short)hb_;
            l[i] = (short)f2bf(wv - bf2f(hb_));
        }
        wh[c] = h; wl[c] = l;
    }
    float bv = bias[col];
    const int srow = tid >> 4, sc4 = (tid & 15) * 4;

    for (int t = 0; t < DNT; ++t) {
        int r0 = (blockIdx.x * DNT + t) * 16;
        size_t rb = ((size_t)(r0 + srow) << 6) + sc4;
        {
            float4 v = *(const float4*)&x[rb];
            const float* vp = (const float*)&v;
            ushort4 hv, lv;
#pragma unroll
            for (int i = 0; i < 4; ++i) {
                u16 hb_ = f2bf(vp[i]);
                ((u16*)&hv)[i] = hb_;
                ((u16*)&lv)[i] = f2bf(vp[i] - bf2f(hb_));
            }
            *(ushort4*)&Ah[srow * LSTR + sc4] = hv;
            *(ushort4*)&Al[srow * LSTR + sc4] = lv;
        }
        *(ushort4*)&Ah[srow * LSTR + 64 + sc4] = *(const ushort4*)&a1h[rb];
        *(ushort4*)&Al[srow * LSTR + 64 + sc4] = *(const ushort4*)&a1l[rb];
        *(ushort4*)&Ah[srow * LSTR + 128 + sc4] = *(const ushort4*)&a2h[rb];
        *(ushort4*)&Al[srow * LSTR + 128 + sc4] = *(const ushort4*)&a2l[rb];
        __syncthreads();

        f32x4 acc = {bv, bv, bv, bv};
#pragma unroll
        for (int c = 0; c < 6; ++c) {
            bf16x8 ah = *(const bf16x8*)&Ah[lrow * LSTR + c * 32 + lk8];
            bf16x8 al = *(const bf16x8*)&Al[lrow * LSTR + c * 32 + lk8];
            acc = __builtin_amdgcn_mfma_f32_16x16x32_bf16(ah, wh[c], acc, 0, 0, 0);
            acc = __builtin_amdgcn_mfma_f32_16x16x32_bf16(al, wh[c], acc, 0, 0, 0);
            acc = __builtin_amdgcn_mfma_f32_16x16x32_bf16(ah, wl[c], acc, 0, 0, 0);
        }
        __syncthreads();

#pragma unroll
        for (int j = 0; j < 4; ++j) {
            int row = r0 + (lane >> 4) * 4 + j;
            float v = fmaxf(acc[j], 0.0f);
            u16 hb_ = f2bf(v);
            ohi[((size_t)row << 6) + col] = hb_;
            olo[((size_t)row << 6) + col] = f2bf(v - bf2f(hb_));
        }
    }
}

__global__ __launch_bounds__(256) void dense2_mf(const u16* __restrict__ a0h,
                                                 const u16* __restrict__ a0l,
                                                 const u16* __restrict__ a1h,
                                                 const u16* __restrict__ a1l,
                                                 const u16* __restrict__ a2h,
                                                 const u16* __restrict__ a2l,
                                                 const float* __restrict__ W,
                                                 const float* __restrict__ bias,
                                                 float* __restrict__ out) {
    __shared__ u16 Ah[16 * LSTR], Al[16 * LSTR];
    __shared__ float Ls[16][48];
    const int tid = threadIdx.x, wid = tid >> 6, lane = tid & 63;
    const int lrow = lane & 15, lk8 = (lane >> 4) * 8;
    const int col = wid * 16 + lrow;
    const bool act = (wid < 3);
    const bool cok = act && (col < NCLS);

    bf16x8 wh[6], wl[6];
#pragma unroll
    for (int c = 0; c < 6; ++c) {
        bf16x8 h = 0, l = 0;
        if (cok) {
#pragma unroll
            for (int i = 0; i < 8; ++i) {
                float wv = W[(c * 32 + lk8 + i) * NCLS + col];
                u16 hb_ = f2bf(wv);
                h[i] = (short)hb_;
                l[i] = (short)f2bf(wv - bf2f(hb_));
            }
        }
        wh[c] = h; wl[c] = l;
    }
    float bv = cok ? bias[col] : 0.0f;
    const int srow = tid >> 4, sc4 = (tid & 15) * 4;

    for (int t = 0; t < DNT; ++t) {
        int r0 = (blockIdx.x * DNT + t) * 16;
        size_t rb = ((size_t)(r0 + srow) << 6) + sc4;
        *(ushort4*)&Ah[srow * LSTR + sc4] = *(const ushort4*)&a0h[rb];
        *(ushort4*)&Al[srow * LSTR + sc4] = *(const ushort4*)&a0l[rb];
        *(ushort4*)&Ah[srow * LSTR + 64 + sc4] = *(const ushort4*)&a1h[rb];
        *(ushort4*)&Al[srow * LSTR + 64 + sc4] = *(const ushort4*)&a1l[rb];
        *(ushort4*)&Ah[srow * LSTR + 128 + sc4] = *(const ushort4*)&a2h[rb];
        *(ushort4*)&Al[srow * LSTR + 128 + sc4] = *(const ushort4*)&a2l[rb];
        __syncthreads();

        if (act) {
            f32x4 acc = {bv, bv, bv, bv};
#pragma unroll
            for (int c = 0; c < 6; ++c) {
                bf16x8 ah = *(const bf16x8*)&Ah[lrow * LSTR + c * 32 + lk8];
                bf16x8 al = *(const bf16x8*)&Al[lrow * LSTR + c * 32 + lk8];
                acc = __builtin_amdgcn_mfma_f32_16x16x32_bf16(ah, wh[c], acc, 0, 0, 0);
                acc = __builtin_amdgcn_mfma_f32_16x16x32_bf16(al, wh[c], acc, 0, 0, 0);
                acc = __builtin_amdgcn_mfma_f32_16x16x32_bf16(ah, wl[c], acc, 0, 0, 0);
            }
#pragma unroll
            for (int j = 0; j < 4; ++j) Ls[(lane >> 4) * 4 + j][col] = acc[j];
        }
        __syncthreads();

        {   // softmax: 16 rows, one 16-lane group per row (4 rows per wave)
            int row = wid * 4 + (lane >> 4);
            int cg = lane & 15;
            float v0 = Ls[row][cg];
            float v1 = Ls[row][cg + 16];
            float v2 = (cg < 8) ? Ls[row][cg + 32] : -1e30f;
            float m = fmaxf(fmaxf(v0, v1), v2);
#pragma unroll
            for (int o = 8; o; o >>= 1) m = fmaxf(m, __shfl_xor(m, o));
            float e0 = expf(v0 - m), e1 = expf(v1 - m);
            float e2 = (cg < 8) ? expf(v2 - m) : 0.0f;
            float s = e0 + e1 + e2;
#pragma unroll
            for (int o = 8; o; o >>= 1) s += __shfl_xor(s, o);
            float inv = 1.0f / s;
            size_t ob = (size_t)(r0 + row) * NCLS;
            out[ob + cg] = e0 * inv;
            out[ob + cg + 16] = e1 * inv;
            if (cg < 8) out[ob + cg + 32] = e2 * inv;
        }
        // next Ls write only happens after the next stage + barrier, so no extra sync
    }
}

// ---------------- host ----------------

extern "C" void kernel_launch(void* const* d_in, const int* in_sizes, int n_in,
                              void* d_out, int out_size, void* d_ws, size_t ws_size,
                              hipStream_t stream) {
    const float* x = (const float*)d_in[0];
    const int* edge_index = (const int*)d_in[1];
    const float* W1 = (const float*)d_in[2];
    const float* b1 = (const float*)d_in[3];
    const float* W2 = (const float*)d_in[4];
    const float* b2 = (const float*)d_in[5];
    float* out = (float*)d_out;

    const int* src = edge_index;
    const int* dst = edge_index + N_EDGES;

    char* ws = (char*)d_ws;
    size_t off = 0;
    auto carve = [&](size_t bytes) -> void* {
        void* p = ws + off;
        off = align256(off + bytes);
        return p;
    };
    int* gFillD = (int*)carve((size_t)NBUCK * 4);
    int* gFillS = (int*)carve((size_t)NBUCK * 4);
    size_t zero_bytes = off;
    int2* partD = (int2*)carve((size_t)NBUCK * CAPE * 8);   // 14.0 MB
    int* partS = (int*)carve((size_t)NBUCK * CAPE * 4);     // 7.0 MB
    int* csr = (int*)carve((size_t)NBUCK * CAPC * 4);       // 8.4 MB
    int2* meta = (int2*)carve((size_t)N_NODES * 8);         // 0.8 MB
    float* dis = (float*)carve((size_t)N_NODES * 4);        // 0.4 MB
    const size_t FB = (size_t)N_NODES * 64 * 2;             // 12.8 MB per bf16 plane
    u16* xb  = (u16*)carve(FB);
    u16* t1h = (u16*)carve(FB);   // Tx1 / Th1 hi
    u16* t1l = (u16*)carve(FB);   // Tx1 / Th1 lo
    u16* t2h = (u16*)carve(FB);   // Tx2 / Th2 hi
    u16* t2l = (u16*)carve(FB);   // Tx2 / Th2 lo
    u16* hh  = (u16*)carve(FB);   // h hi (also gather input for layer 2)
    u16* hl  = (u16*)carve(FB);   // h lo
    // total ~120 MB

    const int WV = (N_NODES * 64) / 256;    // 25000 (one wave per node)

    hipMemsetAsync(d_ws, 0, zero_bytes, stream);

    pscatter_conv<<<PS_BLOCKS + CONV_BLOCKS, 256, 0, stream>>>(src, dst, gFillD, gFillS,
                                                               partD, partS, x, xb);
    build<<<2 * NBUCK, 256, 0, stream>>>(partD, partS, gFillD, gFillS, csr, meta, dis);

    // layer 1
    spmm<<<WV, 256, 0, stream>>>(xb, dis, meta, csr, nullptr, nullptr, nullptr, t1h, t1l);
    spmm<<<WV, 256, 0, stream>>>(t1h, dis, meta, csr, x, nullptr, nullptr, t2h, t2l);
    dense1_mf<<<DGRID, 256, 0, stream>>>(x, t1h, t1l, t2h, t2l, W1, b1, hh, hl);

    // layer 2 (t1/t2 planes reused)
    spmm<<<WV, 256, 0, stream>>>(hh, dis, meta, csr, nullptr, nullptr, nullptr, t1h, t1l);
    spmm<<<WV, 256, 0, stream>>>(t1h, dis, meta, csr, nullptr, hh, hl, t2h, t2l);
    dense2_mf<<<DGRID, 256, 0, stream>>>(hh, hl, t1h, t1l, t2h, t2l, W2, b2, out);
}

// Round 8
// 300.419 us; speedup vs baseline: 2.2960x; 1.2686x over previous
//
#include <hip/hip_runtime.h>

#define N_NODES 100000
#define N_EDGES 1600000
#define NCLS 40
#define NBUCK 196          // buckets of 512 nodes; bucket = id >> 9
#define CAPE 8960          // per-bucket edge capacity
#define CAPC 10752         // per-bucket CSR capacity incl. x8 padding
#define DUMMY N_NODES      // pad source id; dis[DUMMY] = 0, row DUMMY zeroed

typedef unsigned short u16;
typedef unsigned int u32;
typedef short bf16x8 __attribute__((ext_vector_type(8)));
typedef float f32x4 __attribute__((ext_vector_type(4)));

static inline size_t align256(size_t x) { return (x + 255) & ~(size_t)255; }

__device__ __forceinline__ float bf2f(u16 h) { return __uint_as_float(((u32)h) << 16); }
__device__ __forceinline__ u16 f2bf(float f) {
    u32 u = __float_as_uint(f);
    u += 0x7FFFu + ((u >> 16) & 1u);  // round-to-nearest-even
    return (u16)(u >> 16);
}

// ---------- pass 1: LDS-histogram partition by bucket + fused x->bf16 ----------
#define PS_BLOCKS 391
#define CONV_BLOCKS 6250

__global__ __launch_bounds__(256) void pscatter_conv(const int* __restrict__ src,
                                                     const int* __restrict__ dst,
                                                     int* __restrict__ gFillD,
                                                     int* __restrict__ gFillS,
                                                     int2* __restrict__ partD,
                                                     int* __restrict__ partS,
                                                     const float* __restrict__ x,
                                                     u16* __restrict__ xb) {
    if (blockIdx.x >= PS_BLOCKS) {
        int i = (blockIdx.x - PS_BLOCKS) * 256 + threadIdx.x;  // 4 floats/thread
        float4 v = *(const float4*)(x + (size_t)i * 4);
        ushort4 o;
        o.x = f2bf(v.x); o.y = f2bf(v.y); o.z = f2bf(v.z); o.w = f2bf(v.w);
        *(ushort4*)(xb + (size_t)i * 4) = o;
        return;
    }
    __shared__ int histD[NBUCK], histS[NBUCK], chunkD[NBUCK], chunkS[NBUCK];
    int tid = threadIdx.x;
    int base = blockIdx.x * 4096;

    int4 sv[4], dv[4];
#pragma unroll
    for (int j = 0; j < 4; ++j) {
        int idx = base + j * 1024 + tid * 4;
        if (idx < N_EDGES) {
            sv[j] = *(const int4*)(src + idx);
            dv[j] = *(const int4*)(dst + idx);
        } else {
            sv[j] = make_int4(0, 0, 0, 0);
            dv[j] = make_int4(0, 0, 0, 0);
        }
    }

    for (int i = tid; i < NBUCK; i += 256) { histD[i] = 0; histS[i] = 0; }
    __syncthreads();
#pragma unroll
    for (int j = 0; j < 4; ++j)
#pragma unroll
        for (int k = 0; k < 4; ++k) {
            int s = ((const int*)&sv[j])[k], d = ((const int*)&dv[j])[k];
            if (s != d) {
                atomicAdd(&histD[d >> 9], 1);
                atomicAdd(&histS[s >> 9], 1);
            }
        }
    __syncthreads();
    for (int B = tid; B < NBUCK; B += 256) {
        int cD = histD[B];
        chunkD[B] = cD ? atomicAdd(&gFillD[B], cD) : 0;
        int cS = histS[B];
        chunkS[B] = cS ? atomicAdd(&gFillS[B], cS) : 0;
    }
    __syncthreads();
    for (int i = tid; i < NBUCK; i += 256) { histD[i] = 0; histS[i] = 0; }
    __syncthreads();
#pragma unroll
    for (int j = 0; j < 4; ++j)
#pragma unroll
        for (int k = 0; k < 4; ++k) {
            int s = ((const int*)&sv[j])[k], d = ((const int*)&dv[j])[k];
            if (s != d) {
                int bD = d >> 9;
                int r = atomicAdd(&histD[bD], 1);
                int o = chunkD[bD] + r;
                if (o < CAPE) partD[bD * CAPE + o] = make_int2(d, s);
                int bS = s >> 9;
                int r2 = atomicAdd(&histS[bS], 1);
                int o2 = chunkS[bS] + r2;
                if (o2 < CAPE) partS[bS * CAPE + o2] = s;
            }
        }
}

// ---------- pass 2: per-bucket CSR build (blocks [0,196)) / deg->dis (blocks [196,392)) ----------
__global__ __launch_bounds__(256) void build(const int2* __restrict__ partD,
                                             const int* __restrict__ partS,
                                             const int* __restrict__ gFillD,
                                             const int* __restrict__ gFillS,
                                             int* __restrict__ csr,
                                             int2* __restrict__ meta,
                                             float* __restrict__ dis) {
    __shared__ int cnt[512], loc[512], rnk[512];
    int tid = threadIdx.x;

    if (blockIdx.x >= NBUCK) {
        int B = blockIdx.x - NBUCK;
        for (int i = tid; i < 512; i += 256) cnt[i] = 0;
        __syncthreads();
        int nS = min(gFillS[B], CAPE);
        for (int i = tid; i < nS; i += 256) atomicAdd(&cnt[partS[B * CAPE + i] & 511], 1);
        __syncthreads();
        for (int n = tid; n < 512; n += 256) {
            int node = B * 512 + n;
            if (node < N_NODES) {
                int dg = cnt[n];
                dis[node] = dg > 0 ? 1.0f / sqrtf((float)dg) : 0.0f;
            }
        }
        return;
    }

    int B = blockIdx.x;
    for (int i = tid; i < 512; i += 256) { cnt[i] = 0; rnk[i] = 0; }
    __syncthreads();
    int nD = min(gFillD[B], CAPE);
    for (int i = tid; i < nD; i += 256) atomicAdd(&cnt[partD[B * CAPE + i].x & 511], 1);
    __syncthreads();
    if (tid < 64) {
        int bb = tid * 8, c8[8], mysum = 0;
#pragma unroll
        for (int j = 0; j < 8; ++j) { c8[j] = (cnt[bb + j] + 7) & ~7; mysum += c8[j]; }
        int incl = mysum;
#pragma unroll
        for (int off = 1; off < 64; off <<= 1) {
            int v = __shfl_up(incl, off);
            if (tid >= off) incl += v;
        }
        int run = incl - mysum;
#pragma unroll
        for (int j = 0; j < 8; ++j) { loc[bb + j] = run; run += c8[j]; }
    }
    __syncthreads();
    for (int n = tid; n < 512; n += 256) {
        int node = B * 512 + n;
        if (node < N_NODES) {
            meta[node] = make_int2(B * CAPC + loc[n], cnt[n]);
            int c = cnt[n], c8 = (c + 7) & ~7;   // pad list to x8 with DUMMY (w=0)
            for (int e = c; e < c8; ++e) csr[B * CAPC + loc[n] + e] = DUMMY;
        }
    }
    for (int i = tid; i < nD; i += 256) {
        int2 p = partD[B * CAPE + i];
        int ln = p.x & 511;
        int r = atomicAdd(&rnk[ln], 1);
        int pos = loc[ln] + r;
        if (pos < CAPC) csr[B * CAPC + pos] = p.y;
    }
}

// ---------- SPMM pair-gather (one wave/node; 2 edges per load instruction) ----------
// lanes 0-31: even edges, lanes 32-63: odd edges; each lane covers 2 features (u32).
// acc = sum_e dis[s_e]*in[s_e,:];  v = -dis[node]*acc;  sub variants as before.
// half 0 writes the hi bf16 plane, half 1 the lo plane.
__global__ __launch_bounds__(256) void spmm(const u16* __restrict__ in,     // (N+1)x64 bf16
                                            const float* __restrict__ dis,  // N+1, dis[N]=0
                                            const int2* __restrict__ meta,
                                            const int* __restrict__ csr,
                                            const float* __restrict__ subf,
                                            const u16* __restrict__ subh,
                                            const u16* __restrict__ subl,
                                            u16* __restrict__ outhi,
                                            u16* __restrict__ outlo) {
    int node = (blockIdx.x * 256 + threadIdx.x) >> 6;
    int lane = threadIdx.x & 63;
    if (node >= N_NODES) return;
    int2 mt = meta[node];
    int c8 = (mt.y + 7) & ~7;          // lists DUMMY-padded to x8
    const int* lst = csr + mt.x;       // 32B-aligned
    const u32* in32 = (const u32*)in;
    const int hsel = lane >> 5;
    const int fl = lane & 31;
    float acc0 = 0.0f, acc1 = 0.0f;
    for (int e = 0; e < c8; e += 8) {
        int4 sa = *(const int4*)(lst + e);
        int4 sb = *(const int4*)(lst + e + 4);
        int s0 = hsel ? sa.y : sa.x;
        int s1 = hsel ? sa.w : sa.z;
        int s2 = hsel ? sb.y : sb.x;
        int s3 = hsel ? sb.w : sb.z;
        u32 v0 = in32[((u32)s0 << 5) + fl];
        u32 v1 = in32[((u32)s1 << 5) + fl];
        u32 v2 = in32[((u32)s2 << 5) + fl];
        u32 v3 = in32[((u32)s3 << 5) + fl];
        float w0 = dis[s0], w1 = dis[s1], w2 = dis[s2], w3 = dis[s3];
        acc0 = fmaf(w0, __uint_as_float(v0 << 16), acc0);
        acc1 = fmaf(w0, __uint_as_float(v0 & 0xFFFF0000u), acc1);
        acc0 = fmaf(w1, __uint_as_float(v1 << 16), acc0);
        acc1 = fmaf(w1, __uint_as_float(v1 & 0xFFFF0000u), acc1);
        acc0 = fmaf(w2, __uint_as_float(v2 << 16), acc0);
        acc1 = fmaf(w2, __uint_as_float(v2 & 0xFFFF0000u), acc1);
        acc0 = fmaf(w3, __uint_as_float(v3 << 16), acc0);
        acc1 = fmaf(w3, __uint_as_float(v3 & 0xFFFF0000u), acc1);
    }
    acc0 += __shfl_xor(acc0, 32);
    acc1 += __shfl_xor(acc1, 32);
    float vd = -dis[node];
    float f0 = vd * acc0, f1 = vd * acc1;
    u32 o32 = ((u32)node << 5) + fl;
    if (subf) {
        float2 sv = ((const float2*)subf)[o32];
        f0 = 2.0f * f0 - sv.x;
        f1 = 2.0f * f1 - sv.y;
    } else if (subh) {
        u32 sh = ((const u32*)subh)[o32];
        u32 sl = ((const u32*)subl)[o32];
        f0 = 2.0f * f0 - (__uint_as_float(sh << 16) + __uint_as_float(sl << 16));
        f1 = 2.0f * f1 - (__uint_as_float(sh & 0xFFFF0000u) + __uint_as_float(sl & 0xFFFF0000u));
    }
    u16 h0 = f2bf(f0), h1 = f2bf(f1);
    if (hsel == 0) {
        ((u32*)outhi)[o32] = (u32)h0 | ((u32)h1 << 16);
    } else {
        u16 l0 = f2bf(f0 - bf2f(h0));
        u16 l1 = f2bf(f1 - bf2f(h1));
        ((u32*)outlo)[o32] = (u32)l0 | ((u32)l1 << 16);
    }
}

// ---------- dense via MFMA with split-bf16 (fp32-equivalent accuracy) ----------
#define DGRID 1250
#define DNT 5              // 1250 * 5 * 16 = 100000 rows exactly
#define LSTR 200           // u16 per LDS row (192 data + 8 pad)

__global__ __launch_bounds__(256) void dense1_mf(const float* __restrict__ x,
                                                 const u16* __restrict__ a1h,
                                                 const u16* __restrict__ a1l,
                                                 const u16* __restrict__ a2h,
                                                 const u16* __restrict__ a2l,
                                                 const float* __restrict__ W,
                                                 const float* __restrict__ bias,
                                                 u16* __restrict__ ohi,
                                                 u16* __restrict__ olo) {
    __shared__ u16 Ah[16 * LSTR], Al[16 * LSTR];
    const int tid = threadIdx.x, wid = tid >> 6, lane = tid & 63;
    const int lrow = lane & 15, lk8 = (lane >> 4) * 8;
    const int col = wid * 16 + lrow;

    bf16x8 wh[6], wl[6];
#pragma unroll
    for (int c = 0; c < 6; ++c) {
        bf16x8 h, l;
#pragma unroll
        for (int i = 0; i < 8; ++i) {
            float wv = W[(c * 32 + lk8 + i) * 64 + col];
            u16 hb_ = f2bf(wv);
            h[i] = (short)hb_;
            l[i] = (short)f2bf(wv - bf2f(hb_));
        }
        wh[c] = h; wl[c] = l;
    }
    float bv = bias[col];
    const int srow = tid >> 4, sc4 = (tid & 15) * 4;

    for (int t = 0; t < DNT; ++t) {
        int r0 = (blockIdx.x * DNT + t) * 16;
        size_t rb = ((size_t)(r0 + srow) << 6) + sc4;
        {
            float4 v = *(const float4*)&x[rb];
            const float* vp = (const float*)&v;
            ushort4 hv, lv;
#pragma unroll
            for (int i = 0; i < 4; ++i) {
                u16 hb_ = f2bf(vp[i]);
                ((u16*)&hv)[i] = hb_;
                ((u16*)&lv)[i] = f2bf(vp[i] - bf2f(hb_));
            }
            *(ushort4*)&Ah[srow * LSTR + sc4] = hv;
            *(ushort4*)&Al[srow * LSTR + sc4] = lv;
        }
        *(ushort4*)&Ah[srow * LSTR + 64 + sc4] = *(const ushort4*)&a1h[rb];
        *(ushort4*)&Al[srow * LSTR + 64 + sc4] = *(const ushort4*)&a1l[rb];
        *(ushort4*)&Ah[srow * LSTR + 128 + sc4] = *(const ushort4*)&a2h[rb];
        *(ushort4*)&Al[srow * LSTR + 128 + sc4] = *(const ushort4*)&a2l[rb];
        __syncthreads();

        f32x4 acc = {bv, bv, bv, bv};
#pragma unroll
        for (int c = 0; c < 6; ++c) {
            bf16x8 ah = *(const bf16x8*)&Ah[lrow * LSTR + c * 32 + lk8];
            bf16x8 al = *(const bf16x8*)&Al[lrow * LSTR + c * 32 + lk8];
            acc = __builtin_amdgcn_mfma_f32_16x16x32_bf16(ah, wh[c], acc, 0, 0, 0);
            acc = __builtin_amdgcn_mfma_f32_16x16x32_bf16(al, wh[c], acc, 0, 0, 0);
            acc = __builtin_amdgcn_mfma_f32_16x16x32_bf16(ah, wl[c], acc, 0, 0, 0);
        }
        __syncthreads();

#pragma unroll
        for (int j = 0; j < 4; ++j) {
            int row = r0 + (lane >> 4) * 4 + j;
            float v = fmaxf(acc[j], 0.0f);
            u16 hb_ = f2bf(v);
            ohi[((size_t)row << 6) + col] = hb_;
            olo[((size_t)row << 6) + col] = f2bf(v - bf2f(hb_));
        }
    }
}

__global__ __launch_bounds__(256) void dense2_mf(const u16* __restrict__ a0h,
                                                 const u16* __restrict__ a0l,
                                                 const u16* __restrict__ a1h,
                                                 const u16* __restrict__ a1l,
                                                 const u16* __restrict__ a2h,
                                                 const u16* __restrict__ a2l,
                                                 const float* __restrict__ W,
                                                 const float* __restrict__ bias,
                                                 float* __restrict__ out) {
    __shared__ u16 Ah[16 * LSTR], Al[16 * LSTR];
    __shared__ float Ls[16][48];
    const int tid = threadIdx.x, wid = tid >> 6, lane = tid & 63;
    const int lrow = lane & 15, lk8 = (lane >> 4) * 8;
    const int col = wid * 16 + lrow;
    const bool act = (wid < 3);
    const bool cok = act && (col < NCLS);

    bf16x8 wh[6], wl[6];
#pragma unroll
    for (int c = 0; c < 6; ++c) {
        bf16x8 h = 0, l = 0;
        if (cok) {
#pragma unroll
            for (int i = 0; i < 8; ++i) {
                float wv = W[(c * 32 + lk8 + i) * NCLS + col];
                u16 hb_ = f2bf(wv);
                h[i] = (short)hb_;
                l[i] = (short)f2bf(wv - bf2f(hb_));
            }
        }
        wh[c] = h; wl[c] = l;
    }
    float bv = cok ? bias[col] : 0.0f;
    const int srow = tid >> 4, sc4 = (tid & 15) * 4;

    for (int t = 0; t < DNT; ++t) {
        int r0 = (blockIdx.x * DNT + t) * 16;
        size_t rb = ((size_t)(r0 + srow) << 6) + sc4;
        *(ushort4*)&Ah[srow * LSTR + sc4] = *(const ushort4*)&a0h[rb];
        *(ushort4*)&Al[srow * LSTR + sc4] = *(const ushort4*)&a0l[rb];
        *(ushort4*)&Ah[srow * LSTR + 64 + sc4] = *(const ushort4*)&a1h[rb];
        *(ushort4*)&Al[srow * LSTR + 64 + sc4] = *(const ushort4*)&a1l[rb];
        *(ushort4*)&Ah[srow * LSTR + 128 + sc4] = *(const ushort4*)&a2h[rb];
        *(ushort4*)&Al[srow * LSTR + 128 + sc4] = *(const ushort4*)&a2l[rb];
        __syncthreads();

        if (act) {
            f32x4 acc = {bv, bv, bv, bv};
#pragma unroll
            for (int c = 0; c < 6; ++c) {
                bf16x8 ah = *(const bf16x8*)&Ah[lrow * LSTR + c * 32 + lk8];
                bf16x8 al = *(const bf16x8*)&Al[lrow * LSTR + c * 32 + lk8];
                acc = __builtin_amdgcn_mfma_f32_16x16x32_bf16(ah, wh[c], acc, 0, 0, 0);
                acc = __builtin_amdgcn_mfma_f32_16x16x32_bf16(al, wh[c], acc, 0, 0, 0);
                acc = __builtin_amdgcn_mfma_f32_16x16x32_bf16(ah, wl[c], acc, 0, 0, 0);
            }
#pragma unroll
            for (int j = 0; j < 4; ++j) Ls[(lane >> 4) * 4 + j][col] = acc[j];
        }
        __syncthreads();

        {   // softmax: 16 rows, one 16-lane group per row (4 rows per wave)
            int row = wid * 4 + (lane >> 4);
            int cg = lane & 15;
            float v0 = Ls[row][cg];
            float v1 = Ls[row][cg + 16];
            float v2 = (cg < 8) ? Ls[row][cg + 32] : -1e30f;
            float m = fmaxf(fmaxf(v0, v1), v2);
#pragma unroll
            for (int o = 8; o; o >>= 1) m = fmaxf(m, __shfl_xor(m, o));
            float e0 = expf(v0 - m), e1 = expf(v1 - m);
            float e2 = (cg < 8) ? expf(v2 - m) : 0.0f;
            float s = e0 + e1 + e2;
#pragma unroll
            for (int o = 8; o; o >>= 1) s += __shfl_xor(s, o);
            float inv = 1.0f / s;
            size_t ob = (size_t)(r0 + row) * NCLS;
            out[ob + cg] = e0 * inv;
            out[ob + cg + 16] = e1 * inv;
            if (cg < 8) out[ob + cg + 32] = e2 * inv;
        }
    }
}

// ---------------- host ----------------

extern "C" void kernel_launch(void* const* d_in, const int* in_sizes, int n_in,
                              void* d_out, int out_size, void* d_ws, size_t ws_size,
                              hipStream_t stream) {
    const float* x = (const float*)d_in[0];
    const int* edge_index = (const int*)d_in[1];
    const float* W1 = (const float*)d_in[2];
    const float* b1 = (const float*)d_in[3];
    const float* W2 = (const float*)d_in[4];
    const float* b2 = (const float*)d_in[5];
    float* out = (float*)d_out;

    const int* src = edge_index;
    const int* dst = edge_index + N_EDGES;

    char* ws = (char*)d_ws;
    size_t off = 0;
    auto carve = [&](size_t bytes) -> void* {
        void* p = ws + off;
        off = align256(off + bytes);
        return p;
    };
    int* gFillD = (int*)carve((size_t)NBUCK * 4);
    int* gFillS = (int*)carve((size_t)NBUCK * 4);
    size_t zero_bytes = off;
    int2* partD = (int2*)carve((size_t)NBUCK * CAPE * 8);   // 14.0 MB
    int* partS = (int*)carve((size_t)NBUCK * CAPE * 4);     // 7.0 MB
    int* csr = (int*)carve((size_t)NBUCK * CAPC * 4);       // 8.4 MB
    int2* meta = (int2*)carve((size_t)N_NODES * 8);         // 0.8 MB
    float* dis = (float*)carve((size_t)(N_NODES + 1) * 4);  // 0.4 MB (+DUMMY)
    const size_t FB = (size_t)(N_NODES + 1) * 64 * 2;       // 12.8 MB per bf16 plane (+DUMMY row)
    u16* xb  = (u16*)carve(FB);
    u16* t1h = (u16*)carve(FB);   // Tx1 / Th1 hi
    u16* t1l = (u16*)carve(FB);   // Tx1 / Th1 lo
    u16* t2h = (u16*)carve(FB);   // Tx2 / Th2 hi
    u16* t2l = (u16*)carve(FB);   // Tx2 / Th2 lo
    u16* hh  = (u16*)carve(FB);   // h hi (gather input for layer 2)
    u16* hl  = (u16*)carve(FB);   // h lo
    // total ~120 MB

    const int WV = (N_NODES * 64) / 256;    // 25000 (one wave per node)

    hipMemsetAsync(d_ws, 0, zero_bytes, stream);
    hipMemsetAsync(dis + N_NODES, 0, 4, stream);               // dis[DUMMY] = 0
    hipMemsetAsync(xb + (size_t)N_NODES * 64, 0, 128, stream); // zero DUMMY rows of
    hipMemsetAsync(t1h + (size_t)N_NODES * 64, 0, 128, stream);//   all gather inputs
    hipMemsetAsync(hh + (size_t)N_NODES * 64, 0, 128, stream);

    pscatter_conv<<<PS_BLOCKS + CONV_BLOCKS, 256, 0, stream>>>(src, dst, gFillD, gFillS,
                                                               partD, partS, x, xb);
    build<<<2 * NBUCK, 256, 0, stream>>>(partD, partS, gFillD, gFillS, csr, meta, dis);

    // layer 1
    spmm<<<WV, 256, 0, stream>>>(xb, dis, meta, csr, nullptr, nullptr, nullptr, t1h, t1l);
    spmm<<<WV, 256, 0, stream>>>(t1h, dis, meta, csr, x, nullptr, nullptr, t2h, t2l);
    dense1_mf<<<DGRID, 256, 0, stream>>>(x, t1h, t1l, t2h, t2l, W1, b1, hh, hl);

    // layer 2 (t1/t2 planes reused)
    spmm<<<WV, 256, 0, stream>>>(hh, dis, meta, csr, nullptr, nullptr, nullptr, t1h, t1l);
    spmm<<<WV, 256, 0, stream>>>(t1h, dis, meta, csr, nullptr, hh, hl, t2h, t2l);
    dense2_mf<<<DGRID, 256, 0, stream>>>(hh, hl, t1h, t1l, t2h, t2l, W2, b2, out);
}